// Round 14
// baseline (188.614 us; speedup 1.0000x reference)
//
#include <hip/hip_runtime.h>

// out[s, j] = dot(z[s,:], W[c[s]*12288 + j, :]) + b[c[s]*12288 + j]
// z: [1024,128] f32, c: [1024] int, W: [196608,128] f32, b: [196608] f32
// out: [1024, 12288] f32
//
// R13: two-kernel, zero-barrier structure.
//  - build_lists (1 block, once): per-expert sample lists -> d_ws.
//  - expert_mfma: NO LDS, NO barriers. W B-frags in registers (once per
//    block); z A-frags loaded per-lane straight from global (z is 512 KB,
//    L2-resident; 4x intra-block redundancy is ~6 us of L2 traffic) and
//    converted f32->bf16 in-register. m-loop = load->cvt->MFMA->store,
//    fully pipelineable, waves free-running at high occupancy.
// Numerics: pure bf16 RNE operands + f32 MFMA accum (R12-verified:
// absmax 0.0078 vs threshold 0.0253).

#define Z_DIM  128
#define OPE    12288
#define NEXP   16
#define NT     256        // 4 waves
#define NCOLS  128        // output cols per block (2 x 16 per wave)

typedef __attribute__((ext_vector_type(8))) short short8;   // 8 bf16
typedef __attribute__((ext_vector_type(4))) float f32x4;
typedef unsigned short u16;
typedef unsigned int   u32;

__device__ __forceinline__ u16 f2bf(float f) {   // round-to-nearest-even bf16
    union { float f; u32 u; } a; a.f = f;
    const u32 r = a.u + 0x7FFFu + ((a.u >> 16) & 1u);
    return (u16)(r >> 16);
}
__device__ __forceinline__ u32 pack2(float a, float b) {
    return (u32)f2bf(a) | ((u32)f2bf(b) << 16);
}
union S8 { short8 s; uint4 u; };

// ---- pre-kernel: build per-expert sample lists in workspace (once) ----
// ws layout: int cnt[16] @0 ; u16 lst[16][1024] @64
__global__ __launch_bounds__(256, 1)
void build_lists(const int* __restrict__ c, int* __restrict__ ws_cnt,
                 u16* __restrict__ ws_lst) {
    __shared__ int cnt_sh[NEXP];
    const int tid = threadIdx.x;
    if (tid < NEXP) cnt_sh[tid] = 0;
    __syncthreads();
    const int4 cv = ((const int4*)c)[tid];            // 256*4 = 1024 samples
    int p;
    p = atomicAdd(&cnt_sh[cv.x], 1); ws_lst[cv.x * 1024 + p] = (u16)(tid * 4 + 0);
    p = atomicAdd(&cnt_sh[cv.y], 1); ws_lst[cv.y * 1024 + p] = (u16)(tid * 4 + 1);
    p = atomicAdd(&cnt_sh[cv.z], 1); ws_lst[cv.z * 1024 + p] = (u16)(tid * 4 + 2);
    p = atomicAdd(&cnt_sh[cv.w], 1); ws_lst[cv.w * 1024 + p] = (u16)(tid * 4 + 3);
    __syncthreads();
    if (tid < NEXP) ws_cnt[tid] = cnt_sh[tid];
}

// ---- main kernel: grouped GEMM, no LDS, no barriers ----
__global__ __launch_bounds__(NT, 6)
void expert_mfma(const float* __restrict__ z,
                 const float* __restrict__ W,
                 const float* __restrict__ bias,
                 float* __restrict__ out,
                 const int* __restrict__ ws_cnt,
                 const u16* __restrict__ ws_lst) {
    const int e   = blockIdx.y;
    const int n0  = blockIdx.x * NCOLS;
    const int cnt = ws_cnt[e];
    if (cnt == 0) return;                 // expert 15: unused, uniform exit

    const int tid  = threadIdx.x;
    const int lane = tid & 63;
    const int wv   = tid >> 6;            // wave id 0..3
    const int fr   = lane & 15;           // tile row/col index
    const int kg   = lane >> 4;           // k-group 0..3

    const int col0 = n0 + wv * 16 + fr;
    const int col1 = col0 + 64;
    const float bv0 = bias[(size_t)e * OPE + col0];
    const float bv1 = bias[(size_t)e * OPE + col1];
    const u16* lst  = ws_lst + e * 1024;

    // --- W B-fragments (bf16) in registers, once per block ---
    short8 bh0[4], bh1[4];
    #pragma unroll
    for (int cg = 0; cg < 2; ++cg) {
        const float* wrow = W + ((size_t)e * OPE + (cg ? col1 : col0)) * Z_DIM;
        #pragma unroll
        for (int kk = 0; kk < 4; ++kk) {
            const float* p = wrow + kk * 32 + kg * 8;
            const float4 v0 = *(const float4*)p;
            const float4 v1 = *(const float4*)(p + 4);
            S8 h;
            h.u.x = pack2(v0.x, v0.y); h.u.y = pack2(v0.z, v0.w);
            h.u.z = pack2(v1.x, v1.y); h.u.w = pack2(v1.z, v1.w);
            if (cg) bh1[kk] = h.s; else bh0[kk] = h.s;
        }
    }

    // --- m-loop: 16-row subtiles; A-frag direct from global (L2), no sync ---
    for (int ms = 0; ms < cnt; ms += 16) {
        const int r = min(ms + fr, cnt - 1);          // dup rows masked at store
        const float* zp = z + (size_t)lst[r] * Z_DIM;

        f32x4 acc0 = {0.f, 0.f, 0.f, 0.f};
        f32x4 acc1 = {0.f, 0.f, 0.f, 0.f};
        #pragma unroll
        for (int kk = 0; kk < 4; ++kk) {
            const float* p = zp + kk * 32 + kg * 8;
            const float4 v0 = *(const float4*)p;
            const float4 v1 = *(const float4*)(p + 4);
            S8 a;
            a.u.x = pack2(v0.x, v0.y); a.u.y = pack2(v0.z, v0.w);
            a.u.z = pack2(v1.x, v1.y); a.u.w = pack2(v1.z, v1.w);
            acc0 = __builtin_amdgcn_mfma_f32_16x16x32_bf16(a.s, bh0[kk], acc0, 0, 0, 0);
            acc1 = __builtin_amdgcn_mfma_f32_16x16x32_bf16(a.s, bh1[kk], acc1, 0, 0, 0);
        }
        #pragma unroll
        for (int j = 0; j < 4; ++j) {
            const int rr = ms + kg * 4 + j;
            if (rr < cnt) {
                float* orow = out + (size_t)lst[rr] * OPE;
                orow[col0] = acc0[j] + bv0;
                orow[col1] = acc1[j] + bv1;
            }
        }
    }
}

extern "C" void kernel_launch(void* const* d_in, const int* in_sizes, int n_in,
                              void* d_out, int out_size, void* d_ws, size_t ws_size,
                              hipStream_t stream) {
    const float* z = (const float*)d_in[0];
    const int*   c = (const int*)d_in[1];
    const float* W = (const float*)d_in[2];
    const float* b = (const float*)d_in[3];
    float* out = (float*)d_out;

    int* ws_cnt = (int*)d_ws;                         // 16 ints
    u16* ws_lst = (u16*)((char*)d_ws + 64);           // 16 x 1024 u16

    build_lists<<<1, 256, 0, stream>>>(c, ws_cnt, ws_lst);

    dim3 grid(OPE / NCOLS, NEXP);                     // 96 x 16 = 1536 blocks
    expert_mfma<<<grid, NT, 0, stream>>>(z, W, b, out, ws_cnt, ws_lst);
}